// Round 21
// baseline (178.502 us; speedup 1.0000x reference)
//
#include <hip/hip_runtime.h>
#include <math.h>

#define NN 50000
#define EE 800000
#define DDIM 128
#define NROWS 100000   // B*N
#define NB 49          // ceil(NN/1024) scan blocks
#define NDEGB 3125     // EE/256 degree blocks
#define GEMMB 1563     // ceil(NROWS/64) gemm blocks

typedef __attribute__((ext_vector_type(8))) short bf16x8;
typedef __attribute__((ext_vector_type(4))) float f32x4;

__device__ __forceinline__ float lrelu(float x) { return x > 0.f ? x : 0.2f * x; }
// fast ELU via hardware v_exp_f32 (abs err ~1e-7, validated r13)
__device__ __forceinline__ float eluf(float x)  {
    float e = __expf(x);
    return x > 0.f ? x : e - 1.f;
}

__device__ __forceinline__ unsigned short f2bf(float f) {
    unsigned int u = __float_as_uint(f);
    u += 0x7fffu + ((u >> 16) & 1u);          // RNE
    return (unsigned short)(u >> 16);
}
__device__ __forceinline__ float bflo(unsigned int v) { return __uint_as_float(v << 16); }
__device__ __forceinline__ float bfhi(unsigned int v) { return __uint_as_float(v & 0xffff0000u); }

// ---------------------------------------------------------------------------
// prep: blocks [0,NDEGB) do degree histogram; block NDEGB converts W fp32 ->
// bf16 PRE-SWIZZLED (chunk q of col c at byte c*256 + ((q^(c&15))<<4)).
// ---------------------------------------------------------------------------
__global__ __launch_bounds__(256) void prep_kernel(const int* __restrict__ ei,
                                                   int* __restrict__ deg,
                                                   const float* __restrict__ Wfc,
                                                   unsigned short* __restrict__ Wsw) {
    const int tid = threadIdx.x;
    if (blockIdx.x < NDEGB) {
        int e = blockIdx.x * 256 + tid;        // exact: EE == NDEGB*256
        atomicAdd(&deg[ei[EE + e]], 1);
        return;
    }
    // W prep (one block)
    const int col = tid & 127;
    const int kh  = tid >> 7;                  // 0..1
#pragma unroll
    for (int q8 = 0; q8 < 8; ++q8) {
        int k0 = kh * 64 + q8 * 8;
        float4 w0 = *(const float4*)&Wfc[col * DDIM + k0];
        float4 w1 = *(const float4*)&Wfc[col * DDIM + k0 + 4];
        union { uint4 q4; unsigned short u[8]; } pk;
        pk.u[0] = f2bf(w0.x); pk.u[1] = f2bf(w0.y);
        pk.u[2] = f2bf(w0.z); pk.u[3] = f2bf(w0.w);
        pk.u[4] = f2bf(w1.x); pk.u[5] = f2bf(w1.y);
        pk.u[6] = f2bf(w1.z); pk.u[7] = f2bf(w1.w);
        int chunk = (k0 >> 3) ^ (col & 15);
        *(uint4*)((char*)Wsw + col * 256 + chunk * 16) = pk.q4;
    }
}

// ---------------------------------------------------------------------------
// scan1: per-block exclusive scan (block-local offs) + block sums
// ---------------------------------------------------------------------------
__global__ __launch_bounds__(1024) void scan1_kernel(const int* __restrict__ deg,
                                                     int* __restrict__ offs,
                                                     int* __restrict__ bsum) {
    __shared__ int wsum[16];
    const int tid = threadIdx.x, lane = tid & 63, wid = tid >> 6;
    const int i = blockIdx.x * 1024 + tid;
    int v = (i < NN) ? deg[i] : 0;
    int x = v;
#pragma unroll
    for (int o = 1; o < 64; o <<= 1) {
        int t = __shfl_up(x, o);
        if (lane >= o) x += t;
    }
    if (lane == 63) wsum[wid] = x;
    __syncthreads();
    if (wid == 0) {
        int s = (lane < 16) ? wsum[lane] : 0;
#pragma unroll
        for (int o = 1; o < 16; o <<= 1) {
            int t = __shfl_up(s, o);
            if (lane >= o) s += t;
        }
        if (lane < 16) wsum[lane] = s;
    }
    __syncthreads();
    int waveoff = (wid > 0) ? wsum[wid - 1] : 0;
    if (i < NN) offs[i] = x - v + waveoff;          // block-local exclusive
    if (tid == 0) bsum[blockIdx.x] = wsum[15];      // block total
}

// scan2: single wave scans NB block sums -> exclusive bscan.
// offs[NN] in LOCAL representation so offs[NN]+bscan[NB-1] == EE.
__global__ __launch_bounds__(64) void scan2_kernel(const int* __restrict__ bsum,
                                                   int* __restrict__ bscan,
                                                   int* __restrict__ offs) {
    const int lane = threadIdx.x;
    int v = (lane < NB) ? bsum[lane] : 0;
    int x = v;
#pragma unroll
    for (int o = 1; o < 64; o <<= 1) {
        int t = __shfl_up(x, o);
        if (lane >= o) x += t;
    }
    if (lane < NB) bscan[lane] = x - v;
    if (lane == NB - 1) offs[NN] = v;               // local repr of total
}

// ---------------------------------------------------------------------------
// fused: blocks [0,NDEGB) = scatter (latency-bound, fills machine first);
// blocks [NDEGB, NDEGB+GEMMB) = MFMA gemm (memory/MFMA-bound, streams behind).
// Independent work — scatter needs offs/bscan; gemm needs Wsw.
// ---------------------------------------------------------------------------
__global__ __launch_bounds__(256) void fused_kernel(const float* __restrict__ h,
                                                    const unsigned short* __restrict__ Wsw,
                                                    const float* __restrict__ Wat,
                                                    unsigned short* __restrict__ Wh16,
                                                    float* __restrict__ ssrc,
                                                    float* __restrict__ sdst,
                                                    const int* __restrict__ ei,
                                                    const int* __restrict__ offs,
                                                    const int* __restrict__ bscan,
                                                    int* __restrict__ cnt2,
                                                    int* __restrict__ slist) {
    __shared__ unsigned int Wlds_u32[8192];    // 32 KB: 128 cols x 256 B
    __shared__ unsigned short stage[64 * 136]; // 17408 B: 64 rows x 272 B
    const int tid = threadIdx.x;

    if (blockIdx.x < NDEGB) {
        // ---- scatter path: slot via atomic + 4B src write ----
        int e = blockIdx.x * 256 + tid;        // exact: EE == NDEGB*256
        int dst = ei[EE + e];
        int src = ei[e];
        int p = offs[dst] + bscan[dst >> 10] + atomicAdd(&cnt2[dst], 1);
        slist[p] = src;
        return;
    }

    // ---- gemm path ----
    char* WldsB  = (char*)Wlds_u32;
    char* stageB = (char*)stage;
    const int gb   = blockIdx.x - NDEGB;
    const int lane = tid & 63;
    const int wv   = tid >> 6;

    // stage W -> LDS: 8 x 1KB async copies per wave (linear)
    {
        const char* gsrc = (const char*)Wsw + wv * 8192 + lane * 16;
        unsigned int* ldst = &Wlds_u32[wv * 2048];   // byte base wv*8192
#pragma unroll
        for (int c8 = 0; c8 < 8; ++c8) {
            __builtin_amdgcn_global_load_lds((const unsigned int*)(gsrc + c8 * 1024),
                                             ldst + c8 * 256, 16, 0, 0);
        }
    }

    const long mbase  = (long)gb * 64 + wv * 16;
    const bool active = (mbase < NROWS);
    const long mload  = active ? mbase : 0;    // clamp OOB reads for tail waves
    const int c  = lane & 15;                  // A row / D col within tile
    const int kg = lane >> 4;                  // k-group 0..3

    // A fragments: global fp32 -> bf16 regs (overlaps W staging)
    union Af { bf16x8 v; unsigned short u[8]; };
    Af af[4];
    const float* arow = h + (mload + c) * DDIM + kg * 8;
#pragma unroll
    for (int kk = 0; kk < 4; ++kk) {
        float4 x = *(const float4*)(arow + kk * 32);
        float4 y = *(const float4*)(arow + kk * 32 + 4);
        af[kk].u[0] = f2bf(x.x); af[kk].u[1] = f2bf(x.y);
        af[kk].u[2] = f2bf(x.z); af[kk].u[3] = f2bf(x.w);
        af[kk].u[4] = f2bf(y.x); af[kk].u[5] = f2bf(y.y);
        af[kk].u[6] = f2bf(y.z); af[kk].u[7] = f2bf(y.w);
    }
    __syncthreads();                           // drains global_load_lds
    if (!active) return;                       // tail waves: no compute/stores

    // MFMA main: 8 col-tiles x 4 k-steps
    f32x4 acc[8];
#pragma unroll
    for (int t = 0; t < 8; ++t) acc[t] = (f32x4){0.f, 0.f, 0.f, 0.f};
#pragma unroll
    for (int t = 0; t < 8; ++t) {
        int colbase = (t * 16 + c) * 256;
        int sw = c << 4;
#pragma unroll
        for (int kk = 0; kk < 4; ++kk) {
            int ba = (colbase + kk * 64 + kg * 16) ^ sw;
            bf16x8 b = *(const bf16x8*)(WldsB + ba);
            acc[t] = __builtin_amdgcn_mfma_f32_16x16x32_bf16(af[kk].v, b, acc[t], 0, 0, 0);
        }
    }

    // acc -> LDS stage (D: col = t*16+c, local row = wv*16 + kg*4 + r)
#pragma unroll
    for (int t = 0; t < 8; ++t) {
#pragma unroll
        for (int r = 0; r < 4; ++r) {
            int lrow = wv * 16 + kg * 4 + r;
            *(unsigned short*)(stageB + lrow * 272 + (t * 16 + c) * 2) = f2bf(acc[t][r]);
        }
    }
    // wave-local readout: wave's 16 rows = contiguous 4KB in global
    {
        const long gbase = mbase * 256;        // byte offset into Wh16
        const int  lbase = wv * 16 * 272;
#pragma unroll
        for (int q = 0; q < 4; ++q) {
            int f = q * 1024 + lane * 16;      // flat byte idx in wave's 4KB
            uint4 v = *(const uint4*)(stageB + lbase + (f >> 8) * 272 + (f & 255));
            *(uint4*)((char*)Wh16 + gbase + f) = v;
        }
    }

    // fused scores (row-indexed)
    float asv[8], adv[8];
#pragma unroll
    for (int t = 0; t < 8; ++t) {
        asv[t] = Wat[t * 16 + c];
        adv[t] = Wat[DDIM + t * 16 + c];
    }
#pragma unroll
    for (int r = 0; r < 4; ++r) {
        float ps = 0.f, pd = 0.f;
#pragma unroll
        for (int t = 0; t < 8; ++t) {
            ps += acc[t][r] * asv[t];
            pd += acc[t][r] * adv[t];
        }
#pragma unroll
        for (int o = 1; o <= 8; o <<= 1) {
            ps += __shfl_xor(ps, o);
            pd += __shfl_xor(pd, o);
        }
        if (c == 0) {
            long row = mbase + kg * 4 + r;
            ssrc[row] = ps;
            sdst[row] = pd;
        }
    }
}

// ---------------------------------------------------------------------------
// aggregate (r16 structure + weight recompute): one wave per (dst, batch);
// b = bid&1 (XCD batch steering). 16 lanes/edge x uint4 = full 256B row;
// 4 edges per load instruction. w recomputed from L2-resident score tables.
// ---------------------------------------------------------------------------
__global__ __launch_bounds__(256) void aggregate_kernel(const unsigned int* __restrict__ Wh16u,
                                                        const int* __restrict__ offs,
                                                        const int* __restrict__ bscan,
                                                        const int* __restrict__ slist,
                                                        const float* __restrict__ ssrc,
                                                        const float* __restrict__ sdst,
                                                        float* __restrict__ out) {
    const int lane = threadIdx.x & 63;
    const int wid  = threadIdx.x >> 6;
    const int bid  = blockIdx.x;
    const int b    = bid & 1;
    const int d    = (bid >> 1) * 4 + wid;

    const int grp = lane >> 4;     // 0..3: which edge of the quad
    const int fl  = lane & 15;     // feature slice (8 feats = 16B)

    float* o = out + ((long)b * NN + d) * DDIM;

    const int base   = offs[d] + bscan[d >> 10];
    const int end    = offs[d + 1] + bscan[(d + 1) >> 10];
    const int degree = end - base;
    if (degree == 0) {
        if (lane < 16) {
            float4 z = {0.f, 0.f, 0.f, 0.f};
            ((float4*)o)[2 * fl]     = z;
            ((float4*)o)[2 * fl + 1] = z;
        }
        return;
    }

    const long boff = (long)b * NN;
    const float sdv = sdst[boff + d];
    const float* ssb = ssrc + boff;
    const unsigned int* WB = Wh16u + boff * 64;

    f32x4 accA = {0,0,0,0}, accB = {0,0,0,0};
    float ds = 0.f;

    for (int ch = 0; ch < degree; ch += 64) {
        int i = ch + lane;
        int s = 0; float w = 0.f;
        if (i < degree) {
            s = slist[base + i];
            w = __expf(lrelu(ssb[s] + sdv));
            ds += w;
        }
        int cnt   = min(64, degree - ch);
        int quads = (cnt + 3) >> 2;
        for (int j = 0; j < quads; ++j) {
            int idx = 4 * j + grp;               // tail lanes carry w=0
            int   sj = __shfl(s, idx);
            float wj = __shfl(w, idx);
            uint4 v = ((const uint4*)(WB + (long)sj * 64))[fl];
            accA.x += wj * bflo(v.x); accA.y += wj * bfhi(v.x);
            accA.z += wj * bflo(v.y); accA.w += wj * bfhi(v.y);
            accB.x += wj * bflo(v.z); accB.y += wj * bfhi(v.z);
            accB.z += wj * bflo(v.w); accB.w += wj * bfhi(v.w);
        }
    }

    // merge the 4 edge-groups (same feature slice at lanes l, l^16, l^32, l^48)
#pragma unroll
    for (int m = 32; m >= 16; m >>= 1) {
        accA.x += __shfl_xor(accA.x, m); accA.y += __shfl_xor(accA.y, m);
        accA.z += __shfl_xor(accA.z, m); accA.w += __shfl_xor(accA.w, m);
        accB.x += __shfl_xor(accB.x, m); accB.y += __shfl_xor(accB.y, m);
        accB.z += __shfl_xor(accB.z, m); accB.w += __shfl_xor(accB.w, m);
    }
#pragma unroll
    for (int m = 32; m > 0; m >>= 1) ds += __shfl_xor(ds, m);
    const float inv = 1.f / ds;

    if (lane < 16) {
        float4 rA = { eluf(accA.x * inv), eluf(accA.y * inv),
                      eluf(accA.z * inv), eluf(accA.w * inv) };
        float4 rB = { eluf(accB.x * inv), eluf(accB.y * inv),
                      eluf(accB.z * inv), eluf(accB.w * inv) };
        ((float4*)o)[2 * fl]     = rA;
        ((float4*)o)[2 * fl + 1] = rB;
    }
}

// ---------------------------------------------------------------------------
extern "C" void kernel_launch(void* const* d_in, const int* in_sizes, int n_in,
                              void* d_out, int out_size, void* d_ws, size_t ws_size,
                              hipStream_t stream) {
    (void)in_sizes; (void)n_in; (void)out_size; (void)ws_size;
    const float* h   = (const float*)d_in[0];
    const int*   ei  = (const int*)d_in[1];
    const float* Wfc = (const float*)d_in[2];
    const float* Wat = (const float*)d_in[3];
    float* out = (float*)d_out;

    char* ws = (char*)d_ws;
    unsigned short* Wh16 = (unsigned short*)(ws + 0);   // 25,600,000 B
    float*  ssrc  = (float*)(ws + 25600000);            //    400,000 B  [row]
    float*  sdst  = (float*)(ws + 26000000);            //    400,000 B
    int*    slist = (int*)  (ws + 26400000);            //  3,200,000 B
    int*    offs  = (int*)  (ws + 29600000);            //    200,448 B
    int*    deg   = (int*)  (ws + 29800448);            //    200,000 B
    int*    cnt2  = (int*)  (ws + 30000448);            //    200,000 B (contiguous w/ deg)
    int*    bsum  = (int*)  (ws + 30200448);            //        256 B
    int*    bscan = (int*)  (ws + 30200704);            //        256 B
    unsigned short* Wsw = (unsigned short*)(ws + 30200960); // 32,768 B pre-swizzled W

    hipMemsetAsync(deg, 0, 400000, stream);   // zero deg + cnt2

    prep_kernel<<<NDEGB + 1, 256, 0, stream>>>(ei, deg, Wfc, Wsw);
    scan1_kernel<<<NB, 1024, 0, stream>>>(deg, offs, bsum);
    scan2_kernel<<<1, 64, 0, stream>>>(bsum, bscan, offs);
    fused_kernel<<<NDEGB + GEMMB, 256, 0, stream>>>(h, Wsw, Wat, Wh16, ssrc, sdst,
                                                    ei, offs, bscan, cnt2, slist);
    aggregate_kernel<<<25000, 256, 0, stream>>>((const unsigned int*)Wh16, offs, bscan,
                                                slist, ssrc, sdst, out);
}